// Round 7
// baseline (984.247 us; speedup 1.0000x reference)
//
#include <hip/hip_runtime.h>
#include <hip/hip_bf16.h>
#include <math.h>

#define N_NODES 20000
#define N_EDGES 320000
#define HH      256
#define GG      128
#define FN      64
#define FE      16

__device__ __forceinline__ float fast_rcp(float x) {
    return __builtin_amdgcn_rcpf(x);
}
__device__ __forceinline__ float fast_sigmoid(float x) {
    return fast_rcp(1.f + __expf(-x));
}
// sigmoid(zi)*tanh(zg) with 2 transcendental + 1 rcp
__device__ __forceinline__ float sig_tanh(float zi, float zg) {
    float u = __expf(-zi);          // sigmoid = 1/(1+u)
    float v = __expf(2.f * zg);     // tanh = (v-1)/(v+1)
    return (v - 1.f) * fast_rcp((1.f + u) * (v + 1.f));
}

// ---------------------------------------------------------------------------
// CSR build: histogram / two-level scan / permuting scatter
// ---------------------------------------------------------------------------
__global__ void hist_k(const int* __restrict__ dst, int* __restrict__ cnt) {
    int e = blockIdx.x * blockDim.x + threadIdx.x;
    if (e < N_EDGES) atomicAdd(&cnt[dst[e]], 1);
}

__global__ __launch_bounds__(256) void scan1_k(const int* __restrict__ cnt,
                                               int* __restrict__ ex,
                                               int* __restrict__ bsum) {
    int b = blockIdx.x, t = threadIdx.x;
    int i = b * 256 + t;
    int v = (i < N_NODES) ? cnt[i] : 0;
    int lane = t & 63, w = t >> 6;
    int incl = v;
#pragma unroll
    for (int off = 1; off < 64; off <<= 1) {
        int u = __shfl_up(incl, off);
        if (lane >= off) incl += u;
    }
    __shared__ int wsum[4];
    if (lane == 63) wsum[w] = incl;
    __syncthreads();
    int woff = 0;
#pragma unroll
    for (int j = 0; j < 4; ++j)
        if (j < w) woff += wsum[j];
    if (i < N_NODES) ex[i] = woff + incl - v;
    if (t == 255) bsum[b] = woff + incl;
}

__global__ __launch_bounds__(128) void scan2_k(int* __restrict__ bsum, int nb) {
    int t = threadIdx.x;
    int v = (t < nb) ? bsum[t] : 0;
    int lane = t & 63, w = t >> 6;
    int incl = v;
#pragma unroll
    for (int off = 1; off < 64; off <<= 1) {
        int u = __shfl_up(incl, off);
        if (lane >= off) incl += u;
    }
    __shared__ int wsum[2];
    if (lane == 63) wsum[w] = incl;
    __syncthreads();
    int woff = (w == 1) ? wsum[0] : 0;
    if (t < nb) bsum[t] = woff + incl - v;
}

__global__ __launch_bounds__(256) void scan3_k(const int* __restrict__ cnt,
                                               const int* __restrict__ bsum,
                                               int* __restrict__ rowst,
                                               int* __restrict__ cursor) {
    int b = blockIdx.x, t = threadIdx.x;
    int i = b * 256 + t;
    if (i < N_NODES) {
        int v = rowst[i] + bsum[b];
        rowst[i] = v;
        cursor[i] = v;
        if (i == N_NODES - 1) rowst[N_NODES] = v + cnt[i];
    }
}

// scatter edges into CSR order, permuting src and the 64B eattr row along
__global__ void scatter_k(const int* __restrict__ src,
                          const int* __restrict__ dst,
                          const float* __restrict__ eattr,
                          int* __restrict__ cursor, int* __restrict__ srcs,
                          float* __restrict__ eattrs) {
    int e = blockIdx.x * blockDim.x + threadIdx.x;
    if (e < N_EDGES) {
        int pos = atomicAdd(&cursor[dst[e]], 1);
        srcs[pos] = src[e];
        const float4* a = (const float4*)(eattr + (size_t)e * FE);
        float4* o = (float4*)(eattrs + (size_t)pos * FE);
        o[0] = a[0];
        o[1] = a[1];
        o[2] = a[2];
        o[3] = a[3];
    }
}

// ---------------------------------------------------------------------------
// Repack LSTM weights, INTERLEAVED: W2 row 2c = i-gate row c (W row c),
// W2 row 2c+1 = g-gate row c (W row 512+c). K = input width (64 node,
// 16 edge). Makes (zi_c, zg_c) adjacent so epilogues can fuse the activation.
// ---------------------------------------------------------------------------
__global__ void repack_k(const float* __restrict__ W, const float* __restrict__ b,
                         float* __restrict__ W2, float* __restrict__ b2, int K) {
    int idx = blockIdx.x * blockDim.x + threadIdx.x;
    if (idx < 512 * K) {
        int r = idx / K, k = idx - r * K;
        int c = r >> 1;
        int rs = (r & 1) ? (512 + c) : c;
        W2[idx] = W[rs * K + k];
    } else if (idx < 512 * K + 512) {
        int r = idx - 512 * K;
        int c = r >> 1;
        int rs = (r & 1) ? (512 + c) : c;
        b2[r] = b[rs];
    }
}

// ---------------------------------------------------------------------------
// Edge LSTM, specialized for K=16: thread = channel c; weights in VGPRs;
// edge-attr row address is wave-uniform -> scalar/broadcast loads; no LDS,
// no barriers. Writes bf16 [E,256] CSR-ordered (wave stores 128B contiguous).
// ---------------------------------------------------------------------------
#define EPB 64
__global__ __launch_bounds__(256, 4) void edge_lstm_k(
    const float* __restrict__ eattrs, const float* __restrict__ W2e,
    const float* __restrict__ b2e, __hip_bfloat16* __restrict__ eacsr) {
    int c = threadIdx.x;  // channel 0..255
    float wi[16], wg[16];
    const float4* w4 = (const float4*)(W2e + (size_t)(2 * c) * FE);
#pragma unroll
    for (int q = 0; q < 4; ++q) {
        float4 a = w4[q];      // row 2c   (i-gate)
        float4 b = w4[q + 4];  // row 2c+1 (g-gate)
        wi[q * 4 + 0] = a.x; wi[q * 4 + 1] = a.y;
        wi[q * 4 + 2] = a.z; wi[q * 4 + 3] = a.w;
        wg[q * 4 + 0] = b.x; wg[q * 4 + 1] = b.y;
        wg[q * 4 + 2] = b.z; wg[q * 4 + 3] = b.w;
    }
    float bi = b2e[2 * c], bg = b2e[2 * c + 1];
    size_t e0 = (size_t)blockIdx.x * EPB;
    const float* base = eattrs + e0 * FE;
#pragma unroll 2
    for (int e = 0; e < EPB; ++e) {
        const float4* ap = (const float4*)(base + e * FE);  // uniform addr
        float4 a0 = ap[0], a1 = ap[1], a2 = ap[2], a3 = ap[3];
        float av[16] = {a0.x, a0.y, a0.z, a0.w, a1.x, a1.y, a1.z, a1.w,
                        a2.x, a2.y, a2.z, a2.w, a3.x, a3.y, a3.z, a3.w};
        float zi = bi, zg = bg;
#pragma unroll
        for (int k = 0; k < FE; ++k) {
            zi += wi[k] * av[k];
            zg += wg[k] * av[k];
        }
        eacsr[(e0 + e) * HH + c] = __float2bfloat16(sig_tanh(zi, zg));
    }
}

// ---------------------------------------------------------------------------
// GENConv edge pass (gather form, softmax with m=0 shift).
// Edge-LSTM pre-computed into eacsr (bf16, CSR-ordered); ~8 VALU ops +
// 2 loads per edge-channel.
// ---------------------------------------------------------------------------
#define NPB 8
__global__ __launch_bounds__(256, 8) void genconv_edge_k(
    const float* __restrict__ hin, const __hip_bfloat16* __restrict__ eacsr,
    const int* __restrict__ srcs, const int* __restrict__ rowst,
    const float* __restrict__ tptr, float* __restrict__ aout) {
    int tid = threadIdx.x;  // channel 0..255
    float tscale = tptr[0];
    int n0 = blockIdx.x * NPB;
    for (int u = 0; u < NPB; ++u) {
        int n = n0 + u;
        if (n >= N_NODES) break;
        int s0 = rowst[n], s1 = rowst[n + 1];
        float hself = hin[(size_t)n * HH + tid];
        float accE0 = 0.f, accWE0 = 0.f, accE1 = 0.f, accWE1 = 0.f;
        int j = s0;
        for (; j + 1 < s1; j += 2) {
            int sn0 = srcs[j], sn1 = srcs[j + 1];
            float ea0 = __bfloat162float(eacsr[(size_t)j * HH + tid]);
            float ea1 = __bfloat162float(eacsr[(size_t)(j + 1) * HH + tid]);
            float h0v = hin[(size_t)sn0 * HH + tid];
            float h1v = hin[(size_t)sn1 * HH + tid];
            float m0 = fmaxf(h0v + ea0, 0.f) + 1e-7f;
            float m1 = fmaxf(h1v + ea1, 0.f) + 1e-7f;
            float p0 = __expf(tscale * m0);
            float p1 = __expf(tscale * m1);
            accE0 += p0;
            accWE0 += p0 * m0;
            accE1 += p1;
            accWE1 += p1 * m1;
        }
        if (j < s1) {
            int sn = srcs[j];
            float eav = __bfloat162float(eacsr[(size_t)j * HH + tid]);
            float hv = hin[(size_t)sn * HH + tid];
            float m0 = fmaxf(hv + eav, 0.f) + 1e-7f;
            float p0 = __expf(tscale * m0);
            accE0 += p0;
            accWE0 += p0 * m0;
        }
        float accE = accE0 + accE1, accWE = accWE0 + accWE1;
        aout[(size_t)n * HH + tid] = hself + accWE / (accE + 1e-16f);
    }
}

// ---------------------------------------------------------------------------
// fp32 GEMM  C[M,NN] = A[M,K] @ B[NN,K]^T  ("NT")
// 128x128 tile, 256 threads, 8x8 microtile (2x2 groups of 4x4 at stride 64),
// register double-buffered staging.
// mode 0: relu(BN(acc+bias)); mode 1: relu(acc+bias); mode 2: acc+bias;
// mode 3: LSTM fuse sigmoid(y0)*tanh(y1) -> fp32, C is [M, NN/2]
// ---------------------------------------------------------------------------
#define TM 128
#define TN 128
#define KB 16
__global__ __launch_bounds__(256, 2) void gemm_nt_k(
    const float* __restrict__ A, const float* __restrict__ B,
    const float* __restrict__ bias, const float* __restrict__ gamma,
    const float* __restrict__ beta, float* __restrict__ C, int M, int NN,
    int K, int mode) {
    __shared__ float As[KB][TM + 4];
    __shared__ float Bs[KB][TN + 4];
    int tid = threadIdx.x;
    int row0 = blockIdx.x * TM, col0 = blockIdx.y * TN;
    int tx = tid & 15, ty = tid >> 4;
    int lr = tid >> 2;       // 0..63
    int lc = (tid & 3) * 4;  // 0,4,8,12
    float4 va[2], vb[2];
#pragma unroll
    for (int h = 0; h < 2; ++h) {
        int r = lr + h * 64;
        int gr = row0 + r;
        va[h] = (gr < M) ? *(const float4*)&A[(size_t)gr * K + lc]
                         : make_float4(0.f, 0.f, 0.f, 0.f);
        vb[h] = *(const float4*)&B[(size_t)(col0 + r) * K + lc];
    }
    float acc[8][8] = {{0.f}};
    for (int k0 = 0; k0 < K; k0 += KB) {
#pragma unroll
        for (int h = 0; h < 2; ++h) {
            int r = lr + h * 64;
            As[lc + 0][r] = va[h].x;
            As[lc + 1][r] = va[h].y;
            As[lc + 2][r] = va[h].z;
            As[lc + 3][r] = va[h].w;
            Bs[lc + 0][r] = vb[h].x;
            Bs[lc + 1][r] = vb[h].y;
            Bs[lc + 2][r] = vb[h].z;
            Bs[lc + 3][r] = vb[h].w;
        }
        __syncthreads();
        int k1 = k0 + KB;
        if (k1 < K) {
#pragma unroll
            for (int h = 0; h < 2; ++h) {
                int r = lr + h * 64;
                int gr = row0 + r;
                va[h] = (gr < M)
                            ? *(const float4*)&A[(size_t)gr * K + k1 + lc]
                            : make_float4(0.f, 0.f, 0.f, 0.f);
                vb[h] = *(const float4*)&B[(size_t)(col0 + r) * K + k1 + lc];
            }
        }
#pragma unroll
        for (int k = 0; k < KB; ++k) {
            float4 a0 = *(const float4*)&As[k][ty * 4];
            float4 a1 = *(const float4*)&As[k][64 + ty * 4];
            float4 b0 = *(const float4*)&Bs[k][tx * 4];
            float4 b1 = *(const float4*)&Bs[k][64 + tx * 4];
            float av[8] = {a0.x, a0.y, a0.z, a0.w, a1.x, a1.y, a1.z, a1.w};
            float bv[8] = {b0.x, b0.y, b0.z, b0.w, b1.x, b1.y, b1.z, b1.w};
#pragma unroll
            for (int i = 0; i < 8; ++i)
#pragma unroll
                for (int j = 0; j < 8; ++j) acc[i][j] += av[i] * bv[j];
        }
        __syncthreads();
    }
    const float bn_rs = rsqrtf(1.f + 1e-5f);
#pragma unroll
    for (int gj = 0; gj < 2; ++gj) {
        int nb = col0 + gj * 64 + tx * 4;
        float bs[4], sc[4], sh[4];
#pragma unroll
        for (int j = 0; j < 4; ++j) {
            bs[j] = bias[nb + j];
            if (mode == 0) {
                sc[j] = gamma[nb + j] * bn_rs;
                sh[j] = beta[nb + j];
            }
        }
#pragma unroll
        for (int gi = 0; gi < 2; ++gi) {
#pragma unroll
            for (int i2 = 0; i2 < 4; ++i2) {
                int m = row0 + gi * 64 + ty * 4 + i2;
                if (m >= M) continue;
                int i = gi * 4 + i2;
                float y[4];
#pragma unroll
                for (int j = 0; j < 4; ++j) {
                    float v = acc[i][gj * 4 + j] + bs[j];
                    if (mode == 0) v = v * sc[j] + sh[j];
                    if (mode == 0 || mode == 1) v = fmaxf(v, 0.f);
                    y[j] = v;
                }
                if (mode == 3) {
                    float2 o;
                    o.x = sig_tanh(y[0], y[1]);
                    o.y = sig_tanh(y[2], y[3]);
                    *(float2*)&C[(size_t)m * (NN / 2) + nb / 2] = o;
                } else {
                    float4 o = {y[0], y[1], y[2], y[3]};
                    *(float4*)&C[(size_t)m * NN + nb] = o;
                }
            }
        }
    }
}

// ---------------------------------------------------------------------------
// Instance norm over sorted batch segments (block = graph, thread = channel)
// ---------------------------------------------------------------------------
__device__ __forceinline__ int lowerb(const int* a, int n, int key) {
    int lo = 0, hi = n;
    while (lo < hi) {
        int mid = (lo + hi) >> 1;
        if (a[mid] < key) lo = mid + 1;
        else hi = mid;
    }
    return lo;
}

__global__ __launch_bounds__(256) void inst_norm_k(
    const float* __restrict__ x, const int* __restrict__ batch,
    float* __restrict__ y) {
    __shared__ int sS, sE;
    int g = blockIdx.x, t = threadIdx.x;
    if (t == 0) {
        sS = lowerb(batch, N_NODES, g);
        sE = lowerb(batch, N_NODES, g + 1);
    }
    __syncthreads();
    int s = sS, e = sE;
    float sum = 0.f, ss = 0.f;
    for (int n = s; n < e; ++n) {
        float v = x[(size_t)n * HH + t];
        sum += v;
        ss += v * v;
    }
    float c = (float)((e - s) > 0 ? (e - s) : 1);
    float mean = sum / c;
    float var = ss / c - mean * mean;
    float inv = rsqrtf(var + 1e-5f);
    for (int n = s; n < e; ++n) {
        float v = x[(size_t)n * HH + t];
        y[(size_t)n * HH + t] = (v - mean) * inv;
    }
}

// ---------------------------------------------------------------------------
// Fused: instance-norm + segment-max pool + linear + sigmoid (block = graph)
// ---------------------------------------------------------------------------
__global__ __launch_bounds__(256) void inpool_k(
    const float* __restrict__ x, const int* __restrict__ batch,
    const float* __restrict__ lw, const float* __restrict__ lb,
    float* __restrict__ out) {
    __shared__ float pooled[HH];
    __shared__ int sS, sE;
    int g = blockIdx.x, t = threadIdx.x;
    if (t == 0) {
        sS = lowerb(batch, N_NODES, g);
        sE = lowerb(batch, N_NODES, g + 1);
    }
    __syncthreads();
    int s = sS, e = sE;
    float sum = 0.f, ss = 0.f;
    for (int n = s; n < e; ++n) {
        float v = x[(size_t)n * HH + t];
        sum += v;
        ss += v * v;
    }
    float c = (float)((e - s) > 0 ? (e - s) : 1);
    float mean = sum / c;
    float var = ss / c - mean * mean;
    float inv = rsqrtf(var + 1e-5f);
    float m = -3.0e38f;
    for (int n = s; n < e; ++n) {
        float v = (x[(size_t)n * HH + t] - mean) * inv;
        m = fmaxf(m, v);
    }
    pooled[t] = (e > s) ? m : 0.f;
    __syncthreads();
    if (t < 10) {
        float acc = lb[t];
        for (int k = 0; k < HH; ++k) acc += pooled[k] * lw[t * HH + k];
        out[g * 10 + t] = fast_sigmoid(acc);
    }
}

// ---------------------------------------------------------------------------
extern "C" void kernel_launch(void* const* d_in, const int* in_sizes, int n_in,
                              void* d_out, int out_size, void* d_ws,
                              size_t ws_size, hipStream_t stream) {
    const float* x      = (const float*)d_in[0];
    const int*   ei     = (const int*)d_in[1];
    const float* eattr  = (const float*)d_in[2];
    const int*   batch  = (const int*)d_in[3];
    const float* nodeW  = (const float*)d_in[4];
    const float* nodeb  = (const float*)d_in[5];
    const float* edgeW  = (const float*)d_in[6];
    const float* edgeb  = (const float*)d_in[7];
    const float* t1     = (const float*)d_in[8];
    const float* g1w1   = (const float*)d_in[9];
    const float* g1b1   = (const float*)d_in[10];
    const float* g1g    = (const float*)d_in[11];
    const float* g1be   = (const float*)d_in[12];
    const float* g1w2   = (const float*)d_in[13];
    const float* g1b2   = (const float*)d_in[14];
    const float* t2     = (const float*)d_in[15];
    const float* g2w1   = (const float*)d_in[16];
    const float* g2b1   = (const float*)d_in[17];
    const float* g2g    = (const float*)d_in[18];
    const float* g2be   = (const float*)d_in[19];
    const float* g2w2   = (const float*)d_in[20];
    const float* g2b2   = (const float*)d_in[21];
    const float* linw   = (const float*)d_in[22];
    const float* linb   = (const float*)d_in[23];
    float* out = (float*)d_out;

    const int* srcA = ei;
    const int* dstA = ei + N_EDGES;

    float* F0  = (float*)d_ws;                   // [N,256]
    float* F1  = F0 + (size_t)N_NODES * HH;      // [N,256]
    float* F2  = F1 + (size_t)N_NODES * HH;      // [N,512]
    float* W2n = F2 + (size_t)N_NODES * 2 * HH;  // 512*64 interleaved
    float* b2n = W2n + 512 * 64;                 // 512
    float* W2e = b2n + 512;                      // 512*16 interleaved
    float* b2e = W2e + 512 * 16;                 // 512
    float* eattrs = b2e + 512;                   // E*16, CSR-ordered
    __hip_bfloat16* eacsr =
        (__hip_bfloat16*)(eattrs + (size_t)N_EDGES * FE);  // [E,256] bf16
    int* cnt    = (int*)(eacsr + (size_t)N_EDGES * HH);
    int* cursor = cnt + N_NODES;
    int* rowst  = cursor + N_NODES;              // N+1
    int* srcs   = rowst + N_NODES + 1;           // E, CSR-ordered
    int* bsum   = srcs + N_EDGES;                // 128

    const int NSCB = (N_NODES + 255) / 256;      // 79

    // --- CSR build ---
    hipMemsetAsync(cnt, 0, N_NODES * sizeof(int), stream);
    hist_k<<<(N_EDGES + 255) / 256, 256, 0, stream>>>(dstA, cnt);
    scan1_k<<<NSCB, 256, 0, stream>>>(cnt, rowst, bsum);
    scan2_k<<<1, 128, 0, stream>>>(bsum, NSCB);
    scan3_k<<<NSCB, 256, 0, stream>>>(cnt, bsum, rowst, cursor);
    scatter_k<<<(N_EDGES + 255) / 256, 256, 0, stream>>>(srcA, dstA, eattr,
                                                         cursor, srcs, eattrs);

    // --- weight repacks (interleaved i/g) ---
    repack_k<<<(512 * 64 + 512 + 255) / 256, 256, 0, stream>>>(nodeW, nodeb,
                                                               W2n, b2n, 64);
    repack_k<<<(512 * 16 + 512 + 255) / 256, 256, 0, stream>>>(edgeW, edgeb,
                                                               W2e, b2e, 16);

    dim3 gemm_grid1((N_NODES + TM - 1) / TM, 512 / TN);
    dim3 gemm_grid2((N_NODES + TM - 1) / TM, 256 / TN);

    // --- node LSTM via GEMM (fused activation, fp32 out) ---
    gemm_nt_k<<<gemm_grid1, 256, 0, stream>>>(x, W2n, b2n, nullptr, nullptr,
                                              F0, N_NODES, 512, 64, 3);
    // --- edge LSTM, specialized K=16 kernel (fused act, bf16 out) ---
    edge_lstm_k<<<N_EDGES / EPB, 256, 0, stream>>>(eattrs, W2e, b2e, eacsr);

    // --- GENConv 1 ---
    genconv_edge_k<<<(N_NODES + NPB - 1) / NPB, 256, 0, stream>>>(
        F0, eacsr, srcs, rowst, t1, F1);
    gemm_nt_k<<<gemm_grid1, 256, 0, stream>>>(F1, g1w1, g1b1, g1g, g1be, F2,
                                              N_NODES, 512, 256, 0);
    gemm_nt_k<<<gemm_grid2, 256, 0, stream>>>(F2, g1w2, g1b2, nullptr, nullptr,
                                              F1, N_NODES, 256, 512, 1);
    inst_norm_k<<<GG, 256, 0, stream>>>(F1, batch, F0);

    // --- GENConv 2 ---
    genconv_edge_k<<<(N_NODES + NPB - 1) / NPB, 256, 0, stream>>>(
        F0, eacsr, srcs, rowst, t2, F1);
    gemm_nt_k<<<gemm_grid1, 256, 0, stream>>>(F1, g2w1, g2b1, g2g, g2be, F2,
                                              N_NODES, 512, 256, 0);
    gemm_nt_k<<<gemm_grid2, 256, 0, stream>>>(F2, g2w2, g2b2, nullptr, nullptr,
                                              F1, N_NODES, 256, 512, 1);

    // --- fused inst-norm + pool + linear + sigmoid ---
    inpool_k<<<GG, 256, 0, stream>>>(F1, batch, linw, linb, out);
}